// Round 11
// baseline (111.496 us; speedup 1.0000x reference)
//
#include <hip/hip_runtime.h>

// Chamfer-with-normals, B=8, C=6 (3 pos + 3 nrm), N=4096, fp32.
// d[i][j] = aa_i + (bb_j + W) + r_i.c_j,  r=(-2p_i, -W bn_i), c=(q_j, an_j)
// (cross-indexed normals; MFMA f16 hi/lo formulation verified absmax=0 R6-R10).
//
// R11: ledger across R7-R10 shows fused ~27us at BOTH 2 and 4 blocks/CU while
// pipe work is only ~5us -> in-order issue stalls inside the wave: (1) per-rt
// MFMA,MFMA,min3x4 makes each min3 RAW-stall ~30cyc on the MFMA 2 insts back;
// (2) A-frag setup: ~400 VALU/thread of fsplit + 4-way quad-DIVERGENT packing.
// Fix: prep kernel emits rows/cols in FINAL fragment layout (rowrec[row][32]
// A-slots with quad expansion baked in; colpack[col][32] B-slots). Fused:
// A-frag = one coalesced 16B load per rt; LDS staging = linear uint4 copy;
// MFMAs batched 8-at-a-time before their min3s (issue distance ~39cyc covers
// MFMA latency; acc live-range 32 VGPR, total ~120 < 128 @ launch_bounds(256,4)).
//   A32 = [rh6,rl0,rl1 | rl2-5,rh0-3 | rh4,rh5,rl0-5 | 1 1 ah al 0000]
//   B32 = [ch6,ch0,ch1 | ch2-5,cl0-3 | cl4,cl5,cl0-5 | bh bl 1 1 0000]
// Layouts m89/m120-verified; D[row=quad*4+reg][col=lane&15].

constexpr int   NPTS  = 4096;
constexpr int   CPB   = 6;
constexpr int   BATCH = 8;
constexpr float W     = 0.001f;

typedef _Float16 f16x8 __attribute__((ext_vector_type(8)));
typedef float    f32x4 __attribute__((ext_vector_type(4)));

#define MFMA32(A_, B_, C_) __builtin_amdgcn_mfma_f32_16x16x32_f16((A_), (B_), (C_), 0, 0, 0)

__device__ inline void fsplit(float x, _Float16& h, _Float16& l) {
    h = (_Float16)x;
    l = (_Float16)(x - (float)h);
}

// min with row_ror:N DPP (16-lane row rotation; all lanes valid) — VALU pipe.
template<int CTRL>
__device__ inline float minror(float v) {
    int s = __float_as_int(v);
    int r = __builtin_amdgcn_update_dpp(s, s, CTRL, 0xF, 0xF, false);
    return fminf(v, __int_as_float(r));
}

__global__ __launch_bounds__(256) void prep_kernel(
    const float* __restrict__ A, const float* __restrict__ B,
    _Float16* __restrict__ rowrec, _Float16* __restrict__ colpack,
    float* __restrict__ out)
{
    const int g = blockIdx.x * 256 + threadIdx.x;   // 0 .. 65535
    if (g == 0) out[0] = 0.f;
    const int j = g & (NPTS - 1), bd = g >> 12, dir = bd >> 3, batch = bd & 7;
    const int bb = batch * CPB * NPTS;
    const float* rowPos = dir ? B : A;
    const float* rowNrm = dir ? A : B;
    const float* colPos = dir ? A : B;
    const float* colNrm = dir ? B : A;
    const _Float16 one = (_Float16)1.f, zz = (_Float16)0.f;

    // ---- row record: 32 f16, final A-fragment slot order
    {
        const float p0 = rowPos[bb + 0*NPTS + j], p1 = rowPos[bb + 1*NPTS + j],
                    p2 = rowPos[bb + 2*NPTS + j];
        const float n0 = rowNrm[bb + 3*NPTS + j], n1 = rowNrm[bb + 4*NPTS + j],
                    n2 = rowNrm[bb + 5*NPTS + j];
        const float r6[6] = {-2.f*p0, -2.f*p1, -2.f*p2, -W*n0, -W*n1, -W*n2};
        const float aa = fmaf(p0, p0, fmaf(p1, p1, p2*p2));
        _Float16 rh[6], rl[6], ah, al;
#pragma unroll
        for (int c = 0; c < 6; ++c) fsplit(r6[c], rh[c], rl[c]);
        fsplit(aa, ah, al);
        f16x8 q0 = {rh[0], rh[1], rh[2], rh[3], rh[4], rh[5], rl[0], rl[1]};
        f16x8 q1 = {rl[2], rl[3], rl[4], rl[5], rh[0], rh[1], rh[2], rh[3]};
        f16x8 q2 = {rh[4], rh[5], rl[0], rl[1], rl[2], rl[3], rl[4], rl[5]};
        f16x8 q3 = {one, one, ah, al, zz, zz, zz, zz};
        _Float16* rp = rowrec + (size_t)g * 32;
        *(f16x8*)(rp)      = q0;
        *(f16x8*)(rp + 8)  = q1;
        *(f16x8*)(rp + 16) = q2;
        *(f16x8*)(rp + 24) = q3;
    }
    // ---- col record: 32 f16, final B-fragment slot order
    {
        const float q0f = colPos[bb + 0*NPTS + j], q1f = colPos[bb + 1*NPTS + j],
                    q2f = colPos[bb + 2*NPTS + j];
        const float n0 = colNrm[bb + 3*NPTS + j], n1 = colNrm[bb + 4*NPTS + j],
                    n2 = colNrm[bb + 5*NPTS + j];
        const float c6[6] = {q0f, q1f, q2f, n0, n1, n2};
        const float bias = fmaf(q0f, q0f, fmaf(q1f, q1f, q2f*q2f)) + W;
        _Float16 ch[6], cl[6], bh, bl;
#pragma unroll
        for (int c = 0; c < 6; ++c) fsplit(c6[c], ch[c], cl[c]);
        fsplit(bias, bh, bl);
        f16x8 v0 = {ch[0], ch[1], ch[2], ch[3], ch[4], ch[5], ch[0], ch[1]};
        f16x8 v1 = {ch[2], ch[3], ch[4], ch[5], cl[0], cl[1], cl[2], cl[3]};
        f16x8 v2 = {cl[4], cl[5], cl[0], cl[1], cl[2], cl[3], cl[4], cl[5]};
        f16x8 v3 = {bh, bl, one, one, zz, zz, zz, zz};
        _Float16* cp = colpack + (size_t)g * 32;
        *(f16x8*)(cp)      = v0;
        *(f16x8*)(cp + 8)  = v1;
        *(f16x8*)(cp + 16) = v2;
        *(f16x8*)(cp + 24) = v3;
    }
}

// Grid: x = rg*8 + s (rg: 8 groups of 512 rows; s: 8 splits of 512 cols),
// y = batch, z = dir => 1024 blocks = 4/CU. 256 thr; wave owns 128 rows (rt=8).
__global__ __launch_bounds__(256, 4) void chamfer_mfma_kernel(
    const _Float16* __restrict__ rowrec, const _Float16* __restrict__ colpack,
    float* __restrict__ partial)
{
    const int dir = blockIdx.z, batch = blockIdx.y, bd = dir * BATCH + batch;
    const int rg = blockIdx.x >> 3, s = blockIdx.x & 7;
    const int tid = threadIdx.x, w = tid >> 6, lane = tid & 63;
    const int quad = lane >> 4, l16 = lane & 15;

    __shared__ alignas(16) _Float16 lds[512 * 32];   // 512 cols x 64B = 32 KB

    // ---- stage cols: linear 32KB copy (coalesced, conflict-free)
    {
        const uint4* src = (const uint4*)(colpack + ((size_t)bd * NPTS + s * 512) * 32);
        uint4* dst = (uint4*)lds;
#pragma unroll
        for (int i = 0; i < 8; ++i) dst[tid + i * 256] = src[tid + i * 256];
    }

    // ---- A-frags: one 16B load per rt; lane addr = row*64B + quad*16B -> 1KB/wave
    f16x8 a[8];
    {
        const f16x8* ar = (const f16x8*)(rowrec + ((size_t)bd * NPTS + rg * 512) * 32);
#pragma unroll
        for (int rt = 0; rt < 8; ++rt)
            a[rt] = ar[(size_t)((w * 8 + rt) * 16 + l16) * 4 + quad];
    }

    float m[8][4];
#pragma unroll
    for (int rt = 0; rt < 8; ++rt)
#pragma unroll
        for (int r_ = 0; r_ < 4; ++r_) m[rt][r_] = 3.4e38f;

    __syncthreads();                        // the kernel's only barrier

    const f16x8* lp = (const f16x8*)lds;    // [col][4 quads of 16B]
    const f32x4 z = {0.f, 0.f, 0.f, 0.f};
#pragma unroll
    for (int ct = 0; ct < 32; ct += 2) {
        const f16x8 b0 = lp[(size_t)(ct * 16 + l16) * 4 + quad];
        const f16x8 b1 = lp[(size_t)((ct + 1) * 16 + l16) * 4 + quad];
        // Batch 8 MFMAs, then their 16 min3s: issue distance covers MFMA latency,
        // acc live-range stays at 32 VGPRs (no spill at the 128-reg budget).
#pragma unroll
        for (int g_ = 0; g_ < 2; ++g_) {
            f32x4 acc0[4], acc1[4];
#pragma unroll
            for (int k = 0; k < 4; ++k) {
                const int rt = g_ * 4 + k;
                acc0[k] = MFMA32(a[rt], b0, z);
                acc1[k] = MFMA32(a[rt], b1, z);
            }
#pragma unroll
            for (int k = 0; k < 4; ++k) {
                const int rt = g_ * 4 + k;
#pragma unroll
                for (int r_ = 0; r_ < 4; ++r_)
                    m[rt][r_] = fminf(m[rt][r_], fminf(acc0[k][r_], acc1[k][r_]));
            }
        }
    }

    // ---- col-min over l16 via DPP row_ror (VALU pipe, no DS traffic)
#pragma unroll
    for (int rt = 0; rt < 8; ++rt)
#pragma unroll
        for (int r_ = 0; r_ < 4; ++r_) {
            float v = m[rt][r_];
            v = minror<0x121>(v);   // ror 1
            v = minror<0x122>(v);   // ror 2
            v = minror<0x124>(v);   // ror 4
            v = minror<0x128>(v);   // ror 8
            m[rt][r_] = v;
        }
    if (l16 == 0) {
        float* pb = partial + (size_t)(s * 16 + bd) * NPTS + rg * 512;
#pragma unroll
        for (int rt = 0; rt < 8; ++rt)
            *(float4*)(pb + (w * 8 + rt) * 16 + quad * 4) =
                make_float4(m[rt][0], m[rt][1], m[rt][2], m[rt][3]);
    }
}

__global__ __launch_bounds__(256) void reduce_kernel(
    const float* __restrict__ partial, float* __restrict__ out)
{
    const int g = blockIdx.x * 256 + threadIdx.x;   // 0 .. 65535
    const int bd = g >> 12, row = g & (NPTS - 1);
    float v = partial[(size_t)(0 * 16 + bd) * NPTS + row];
#pragma unroll
    for (int s = 1; s < 8; ++s)
        v = fminf(v, partial[(size_t)(s * 16 + bd) * NPTS + row]);
    for (int off = 32; off; off >>= 1)
        v += __shfl_down(v, off, 64);
    __shared__ float sred[4];
    if ((threadIdx.x & 63) == 0) sred[threadIdx.x >> 6] = v;
    __syncthreads();
    if (threadIdx.x == 0)
        atomicAdd(out, (sred[0] + sred[1] + sred[2] + sred[3]) * 0.125f);  // /B
}

extern "C" void kernel_launch(void* const* d_in, const int* in_sizes, int n_in,
                              void* d_out, int out_size, void* d_ws, size_t ws_size,
                              hipStream_t stream) {
    const float* A = (const float*)d_in[0];
    const float* B = (const float*)d_in[1];
    float* out     = (float*)d_out;

    // ws: [rowrec 4MB][colpack 4MB][partial 2MB]
    _Float16* rowrec  = (_Float16*)d_ws;
    _Float16* colpack = rowrec + (size_t)2 * BATCH * NPTS * 32;
    float*    partial = (float*)((char*)d_ws + (size_t)8 * 1024 * 1024);

    prep_kernel<<<dim3(2 * BATCH * NPTS / 256), 256, 0, stream>>>(A, B, rowrec, colpack, out);
    chamfer_mfma_kernel<<<dim3(64, BATCH, 2), 256, 0, stream>>>(rowrec, colpack, partial);
    reduce_kernel<<<dim3(2 * BATCH * NPTS / 256), 256, 0, stream>>>(partial, out);
}

// Round 12
// 86.973 us; speedup vs baseline: 1.2820x; 1.2820x over previous
//
#include <hip/hip_runtime.h>

// Chamfer-with-normals, B=8, C=6 (3 pos + 3 nrm), N=4096, fp32.
// d[i][j] = aa_i + (bb_j + W) + r_i.c_j,  r=(-2p_i, -W bn_i), c=(q_j, an_j)
// (cross-indexed normals; MFMA f16 hi/lo formulation verified absmax=0 R6-R11).
//
// R12 = R10 base + three fixes driven by R11's counter evidence:
//  (1) launch_bounds(256,2): 256-VGPR budget. R11's spill (VGPR_Count=64,
//      106MB scratch writes) came from batched accs at a 128-reg budget.
//  (2) b-frag double-buffer: prefetch ct+2 (wrapped index) before consuming
//      ct — hides the ~120cyc LDS latency under the ~256cyc MFMA block.
//      R7/R10's loop consumed ds_read results immediately -> all waves
//      stall in phase on lgkmcnt every iteration (the ~23us plateau).
//  (3) MFMA batching in groups of 4 rt (acc live 32 regs), min3 after each
//      group; PLANAR k-plane LDS layout kept (R11's interleaved layout gave
//      524288 bank conflicts; planar is measured conflict-free).
//   A32 = [rh6|rl6|rh6|rl6| 1 1 ah al |0000], B32 = [ch6|ch6|cl6|cl6| bh bl 1 1 |0000]
// Layouts m89/m120-verified; D[row=quad*4+reg][col=lane&15].

constexpr int   NPTS  = 4096;
constexpr int   CPB   = 6;
constexpr int   BATCH = 8;
constexpr float W     = 0.001f;

typedef _Float16 f16x8 __attribute__((ext_vector_type(8)));
typedef float    f32x4 __attribute__((ext_vector_type(4)));

#define MFMA32(A_, B_, C_) __builtin_amdgcn_mfma_f32_16x16x32_f16((A_), (B_), (C_), 0, 0, 0)

__device__ inline void fsplit(float x, _Float16& h, _Float16& l) {
    h = (_Float16)x;
    l = (_Float16)(x - (float)h);
}

// min with row_ror:N DPP (16-lane row rotation; all lanes valid) — VALU pipe.
template<int CTRL>
__device__ inline float minror(float v) {
    int s = __float_as_int(v);
    int r = __builtin_amdgcn_update_dpp(s, s, CTRL, 0xF, 0xF, false);
    return fminf(v, __int_as_float(r));
}

// Grid: x = rg*8 + s (rg: 8 groups of 512 rows; s: 8 splits of 512 cols),
// y = batch, z = dir => 1024 blocks. 256 thr; wave owns 128 rows (rt=8).
__global__ __launch_bounds__(256, 2) void chamfer_fused_kernel(
    const float* __restrict__ A, const float* __restrict__ B,
    float* __restrict__ partial, float* __restrict__ out)
{
    const int dir = blockIdx.z, batch = blockIdx.y, bd = dir * BATCH + batch;
    const int rg = blockIdx.x >> 3, s = blockIdx.x & 7;
    const int tid = threadIdx.x, w = tid >> 6, lane = tid & 63;
    const int quad = lane >> 4, l16 = lane & 15;
    const float* rowPos = dir ? B : A;
    const float* rowNrm = dir ? A : B;
    const float* colPos = dir ? A : B;
    const float* colNrm = dir ? B : A;
    const int bb = batch * CPB * NPTS;
    const _Float16 one = (_Float16)1.f, zz = (_Float16)0.f;

    if (blockIdx.x == 0 && blockIdx.y == 0 && blockIdx.z == 0 && tid == 0)
        out[0] = 0.f;                       // ordered before reduce's atomics

    // PLANAR [k-plane][col][8 f16]: plane p at p*4096 f16 (8KB); conflict-free
    // b128 pattern for both staging writes and b-frag reads (verified R9/R10).
    __shared__ alignas(16) _Float16 lds[4 * 512 * 8];    // 32 KB

    // ---- stage this block's 512 cols (2 cols per thread)
#pragma unroll
    for (int p = 0; p < 2; ++p) {
        const int j  = p * 256 + tid;
        const int cj = s * 512 + j;
        const float q0 = colPos[bb + 0*NPTS + cj], q1 = colPos[bb + 1*NPTS + cj],
                    q2 = colPos[bb + 2*NPTS + cj];
        const float n0 = colNrm[bb + 3*NPTS + cj], n1 = colNrm[bb + 4*NPTS + cj],
                    n2 = colNrm[bb + 5*NPTS + cj];
        const float c6[6] = {q0, q1, q2, n0, n1, n2};
        const float bias = fmaf(q0, q0, fmaf(q1, q1, q2*q2)) + W;
        _Float16 ch[6], cl[6], bh, bl;
#pragma unroll
        for (int c = 0; c < 6; ++c) fsplit(c6[c], ch[c], cl[c]);
        fsplit(bias, bh, bl);
        f16x8 v0 = {ch[0], ch[1], ch[2], ch[3], ch[4], ch[5], ch[0], ch[1]};
        f16x8 v1 = {ch[2], ch[3], ch[4], ch[5], cl[0], cl[1], cl[2], cl[3]};
        f16x8 v2 = {cl[4], cl[5], cl[0], cl[1], cl[2], cl[3], cl[4], cl[5]};
        f16x8 v3 = {bh, bl, one, one, zz, zz, zz, zz};
        *(f16x8*)&lds[0 * 4096 + j * 8] = v0;
        *(f16x8*)&lds[1 * 4096 + j * 8] = v1;
        *(f16x8*)&lds[2 * 4096 + j * 8] = v2;
        *(f16x8*)&lds[3 * 4096 + j * 8] = v3;
    }

    // ---- A-frags: rt=8 row-tiles per wave (wave owns 128 rows)
    f16x8 a[8];
#pragma unroll
    for (int rt = 0; rt < 8; ++rt) {
        const int row = rg * 512 + (w * 8 + rt) * 16 + l16;
        const float p0 = rowPos[bb + 0*NPTS + row], p1 = rowPos[bb + 1*NPTS + row],
                    p2 = rowPos[bb + 2*NPTS + row];
        const float rn0 = rowNrm[bb + 3*NPTS + row], rn1 = rowNrm[bb + 4*NPTS + row],
                    rn2 = rowNrm[bb + 5*NPTS + row];
        const float r6[6] = {-2.f*p0, -2.f*p1, -2.f*p2, -W*rn0, -W*rn1, -W*rn2};
        const float aa = fmaf(p0, p0, fmaf(p1, p1, p2*p2));
        _Float16 rh[6], rl[6], ah, al;
#pragma unroll
        for (int c = 0; c < 6; ++c) fsplit(r6[c], rh[c], rl[c]);
        fsplit(aa, ah, al);
        f16x8 af;
        if (quad == 0)      af = f16x8{rh[0], rh[1], rh[2], rh[3], rh[4], rh[5], rl[0], rl[1]};
        else if (quad == 1) af = f16x8{rl[2], rl[3], rl[4], rl[5], rh[0], rh[1], rh[2], rh[3]};
        else if (quad == 2) af = f16x8{rh[4], rh[5], rl[0], rl[1], rl[2], rl[3], rl[4], rl[5]};
        else                af = f16x8{one, one, ah, al, zz, zz, zz, zz};
        a[rt] = af;
    }

    float m[8][4];
#pragma unroll
    for (int rt = 0; rt < 8; ++rt)
#pragma unroll
        for (int r_ = 0; r_ < 4; ++r_) m[rt][r_] = 3.4e38f;

    __syncthreads();                        // the kernel's only barrier

    const _Float16* lq = &lds[quad * 4096];
    const f32x4 z = {0.f, 0.f, 0.f, 0.f};

    // Software-pipelined K-loop: b-frags for ct preloaded; prefetch ct+2
    // (wrapped index — last prefetch reads col 0, never consumed) before use.
    f16x8 b0 = *(const f16x8*)&lq[(0 * 16 + l16) * 8];
    f16x8 b1 = *(const f16x8*)&lq[(1 * 16 + l16) * 8];
#pragma unroll 4
    for (int ct = 0; ct < 32; ct += 2) {
        const int ctn = (ct + 2) & 31;
        const f16x8 nb0 = *(const f16x8*)&lq[(ctn * 16 + l16) * 8];
        const f16x8 nb1 = *(const f16x8*)&lq[((ctn + 1) * 16 + l16) * 8];
#pragma unroll
        for (int g_ = 0; g_ < 2; ++g_) {
            f32x4 acc0[4], acc1[4];
#pragma unroll
            for (int k = 0; k < 4; ++k) {
                acc0[k] = MFMA32(a[g_ * 4 + k], b0, z);
                acc1[k] = MFMA32(a[g_ * 4 + k], b1, z);
            }
#pragma unroll
            for (int k = 0; k < 4; ++k) {
                const int rt = g_ * 4 + k;
#pragma unroll
                for (int r_ = 0; r_ < 4; ++r_)
                    m[rt][r_] = fminf(m[rt][r_], fminf(acc0[k][r_], acc1[k][r_]));
            }
        }
        b0 = nb0;
        b1 = nb1;
    }

    // ---- col-min over l16 via DPP row_ror (VALU pipe, no DS traffic)
#pragma unroll
    for (int rt = 0; rt < 8; ++rt)
#pragma unroll
        for (int r_ = 0; r_ < 4; ++r_) {
            float v = m[rt][r_];
            v = minror<0x121>(v);   // ror 1
            v = minror<0x122>(v);   // ror 2
            v = minror<0x124>(v);   // ror 4
            v = minror<0x128>(v);   // ror 8
            m[rt][r_] = v;
        }
    if (l16 == 0) {
        float* pb = partial + (size_t)(s * 16 + bd) * NPTS + rg * 512;
#pragma unroll
        for (int rt = 0; rt < 8; ++rt)
            *(float4*)(pb + (w * 8 + rt) * 16 + quad * 4) =
                make_float4(m[rt][0], m[rt][1], m[rt][2], m[rt][3]);
    }
}

__global__ __launch_bounds__(256) void reduce_kernel(
    const float* __restrict__ partial, float* __restrict__ out)
{
    const int g = blockIdx.x * 256 + threadIdx.x;   // 0 .. 65535
    const int bd = g >> 12, row = g & (NPTS - 1);
    float v = partial[(size_t)(0 * 16 + bd) * NPTS + row];
#pragma unroll
    for (int s = 1; s < 8; ++s)
        v = fminf(v, partial[(size_t)(s * 16 + bd) * NPTS + row]);
    for (int off = 32; off; off >>= 1)
        v += __shfl_down(v, off, 64);
    __shared__ float sred[4];
    if ((threadIdx.x & 63) == 0) sred[threadIdx.x >> 6] = v;
    __syncthreads();
    if (threadIdx.x == 0)
        atomicAdd(out, (sred[0] + sred[1] + sred[2] + sred[3]) * 0.125f);  // /B
}

extern "C" void kernel_launch(void* const* d_in, const int* in_sizes, int n_in,
                              void* d_out, int out_size, void* d_ws, size_t ws_size,
                              hipStream_t stream) {
    const float* A = (const float*)d_in[0];
    const float* B = (const float*)d_in[1];
    float* out     = (float*)d_out;
    float* partial = (float*)d_ws;          // 8 splits x 16 bd x 4096 f32 = 2 MB

    chamfer_fused_kernel<<<dim3(64, BATCH, 2), 256, 0, stream>>>(A, B, partial, out);
    reduce_kernel<<<dim3(2 * BATCH * NPTS / 256), 256, 0, stream>>>(partial, out);
}